// Round 8
// baseline (4629.855 us; speedup 1.0000x reference)
//
#include <hip/hip_runtime.h>
#include <math.h>

#define N_NODES 100000
#define N_EDGES 3200000
#define HDIM 128
#define BSH 9                                   // 512 nodes per dst-bucket
#define NBUCK ((N_NODES + (1 << BSH) - 1) >> BSH)   // 196

typedef __attribute__((ext_vector_type(8))) short bf16x8;
typedef __attribute__((ext_vector_type(4))) float f32x4;

__device__ __forceinline__ unsigned short f2bf(float f) {
  union { float f; unsigned u; } v; v.f = f;
  unsigned r = v.u + 0x7fffu + ((v.u >> 16) & 1u);
  return (unsigned short)(r >> 16);
}
__device__ __forceinline__ float bflo(unsigned p) {
  union { unsigned u; float f; } v; v.u = p << 16; return v.f;
}
__device__ __forceinline__ float bfhi(unsigned p) {
  union { unsigned u; float f; } v; v.u = p & 0xffff0000u; return v.f;
}

// ---------------------------------------------------------------------------
__global__ __launch_bounds__(256) void zero_i32(int* __restrict__ p, int n) {
  int i = blockIdx.x * 256 + threadIdx.x;
  if (i < n) p[i] = 0;
}
__global__ __launch_bounds__(256) void zero_f32(float* __restrict__ p, int n) {
  int i = blockIdx.x * 256 + threadIdx.x;
  if (i < n) p[i] = 0.f;
}
__global__ __launch_bounds__(256) void f32_to_bf16_pack(
    const float* __restrict__ src, unsigned* __restrict__ dst, int n2) {
  int i = blockIdx.x * 256 + threadIdx.x;
  if (i >= n2) return;
  dst[i] = (unsigned)f2bf(src[2 * i]) | ((unsigned)f2bf(src[2 * i + 1]) << 16);
}

// ---------------------------------------------------------------------------
// Repack [384][128] fp32 weights into MFMA-B-fragment-ordered bf16.
// dst[t*2048 + ks*512 + lane*8 + j] = src[(t*16 + (lane&15))*128 + ks*32 + (lane>>4)*8 + j]
// ---------------------------------------------------------------------------
__global__ __launch_bounds__(256) void repack_frag_b(
    const float* __restrict__ src, short* __restrict__ dst)
{
  int o = blockIdx.x * 256 + threadIdx.x;      // 0 .. 384*128-1
  if (o >= 384 * 128) return;
  int j    = o & 7;
  int lane = (o >> 3) & 63;
  int ks   = (o >> 9) & 3;
  int t    = o >> 11;
  int m  = lane & 15;
  int g4 = lane >> 4;
  dst[o] = (short)f2bf(src[(t * 16 + m) * 128 + ks * 32 + g4 * 8 + j]);
}

// ---------------------------------------------------------------------------
// Tiled fp32 GEMM, K fixed at 128 (emb, head, weight folds).
// ---------------------------------------------------------------------------
template<bool BT, bool ACC>
__global__ __launch_bounds__(256) void gemm_k128(
    const float* __restrict__ A, const float* __restrict__ W,
    const float* __restrict__ bias, float* __restrict__ Y,
    int M, int OUT)
{
  __shared__ alignas(16) float lds_a[32 * 68];
  __shared__ alignas(16) float lds_b[32 * 132];
  const int tid = threadIdx.x;
  const int tx = tid & 15;
  const int ty = tid >> 4;
  const int rowBase = blockIdx.x * 64;
  const int colBase = blockIdx.y * 128;

  float acc[4][8];
#pragma unroll
  for (int r = 0; r < 4; r++)
#pragma unroll
    for (int c = 0; c < 8; c++) acc[r][c] = 0.f;

  for (int k0 = 0; k0 < 128; k0 += 32) {
#pragma unroll
    for (int i = 0; i < 2; i++) {
      int idx = tid + i * 256;
      int r   = idx >> 3;
      int kk  = (idx & 7) << 2;
      int gr  = rowBase + r;
      float4 v = make_float4(0.f, 0.f, 0.f, 0.f);
      if (gr < M) v = *(const float4*)(A + (size_t)gr * HDIM + k0 + kk);
      lds_a[(kk + 0) * 68 + r] = v.x;
      lds_a[(kk + 1) * 68 + r] = v.y;
      lds_a[(kk + 2) * 68 + r] = v.z;
      lds_a[(kk + 3) * 68 + r] = v.w;
    }
    if (!BT) {
#pragma unroll
      for (int i = 0; i < 4; i++) {
        int idx = tid + i * 256;
        int kk  = idx >> 5;
        int j   = (idx & 31) << 2;
        int gj  = colBase + j;
        float4 v = make_float4(0.f, 0.f, 0.f, 0.f);
        if (gj < OUT) v = *(const float4*)(W + (size_t)(k0 + kk) * OUT + gj);
        *((float4*)&lds_b[kk * 132 + j]) = v;
      }
    } else {
#pragma unroll
      for (int i = 0; i < 4; i++) {
        int idx = tid + i * 256;
        int j   = idx >> 3;
        int k4  = (idx & 7) << 2;
        int gj  = colBase + j;
        float4 v = make_float4(0.f, 0.f, 0.f, 0.f);
        if (gj < OUT) v = *(const float4*)(W + (size_t)gj * HDIM + k0 + k4);
        lds_b[(k4 + 0) * 132 + j] = v.x;
        lds_b[(k4 + 1) * 132 + j] = v.y;
        lds_b[(k4 + 2) * 132 + j] = v.z;
        lds_b[(k4 + 3) * 132 + j] = v.w;
      }
    }
    __syncthreads();
#pragma unroll 8
    for (int kk = 0; kk < 32; kk++) {
      float4 a4 = *(const float4*)&lds_a[kk * 68 + ty * 4];
      float4 b0 = *(const float4*)&lds_b[kk * 132 + tx * 8];
      float4 b1 = *(const float4*)&lds_b[kk * 132 + tx * 8 + 4];
      float av[4] = {a4.x, a4.y, a4.z, a4.w};
      float bv[8] = {b0.x, b0.y, b0.z, b0.w, b1.x, b1.y, b1.z, b1.w};
#pragma unroll
      for (int r = 0; r < 4; r++)
#pragma unroll
        for (int c = 0; c < 8; c++)
          acc[r][c] = fmaf(av[r], bv[c], acc[r][c]);
    }
    __syncthreads();
  }

  int col = colBase + tx * 8;
  if (col >= OUT) return;
  float bv[8];
#pragma unroll
  for (int c = 0; c < 8; c++) bv[c] = bias ? bias[col + c] : 0.f;
#pragma unroll
  for (int r = 0; r < 4; r++) {
    int gr = rowBase + ty * 4 + r;
    if (gr >= M) continue;
    float* yp = Y + (size_t)gr * OUT + col;
    float4 o0 = make_float4(acc[r][0] + bv[0], acc[r][1] + bv[1],
                            acc[r][2] + bv[2], acc[r][3] + bv[3]);
    float4 o1 = make_float4(acc[r][4] + bv[4], acc[r][5] + bv[5],
                            acc[r][6] + bv[6], acc[r][7] + bv[7]);
    if (ACC) {
      float4 y0 = *(float4*)yp;
      float4 y1 = *(float4*)(yp + 4);
      o0.x += y0.x; o0.y += y0.y; o0.z += y0.z; o0.w += y0.w;
      o1.x += y1.x; o1.y += y1.y; o1.z += y1.z; o1.w += y1.w;
    }
    *(float4*)yp       = o0;
    *(float4*)(yp + 4) = o1;
  }
}

// ---------------------------------------------------------------------------
// CSR build (by destination), edges packed as int2{src, w_bits}.
// Two-pass bucketed scatter: pass1 appends into 196 dst-buckets (hot tail
// lines -> writes ~= data volume); pass2 scatters within the L2-resident
// bucket window. Replaces the 200MB-writeback single-pass fill.
// ---------------------------------------------------------------------------
__global__ __launch_bounds__(256) void csr_hist(
    const int* __restrict__ ei, int* __restrict__ deg)
{
  int e = blockIdx.x * 256 + threadIdx.x;
  if (e < N_EDGES) atomicAdd(&deg[ei[N_EDGES + e]], 1);
}

__global__ __launch_bounds__(256) void scan_blk(
    const int* __restrict__ deg, int* __restrict__ rowptr,
    int* __restrict__ blksum)
{
  __shared__ int lds[256];
  int tid  = threadIdx.x;
  int idx0 = blockIdx.x * 2048 + tid * 8;
  int v[8];
  int local = 0;
#pragma unroll
  for (int j = 0; j < 8; j++) {
    int i = idx0 + j;
    v[j] = (i < N_NODES) ? deg[i] : 0;
    local += v[j];
  }
  lds[tid] = local;
  __syncthreads();
  int inc = local;
  for (int off = 1; off < 256; off <<= 1) {
    int t = (tid >= off) ? lds[tid - off] : 0;
    __syncthreads();
    lds[tid] += t;
    __syncthreads();
  }
  int run = lds[tid] - inc;
#pragma unroll
  for (int j = 0; j < 8; j++) {
    int i = idx0 + j;
    if (i < N_NODES) rowptr[i] = run;
    run += v[j];
  }
  if (tid == 255) blksum[blockIdx.x] = lds[255];
}

__global__ void scan_top(int* __restrict__ blksum, int nblk,
                         int* __restrict__ rowptr)
{
  int tid = threadIdx.x;             // 64 threads
  int orig = (tid < nblk) ? blksum[tid] : 0;
  int v = orig;
  for (int off = 1; off < 64; off <<= 1) {
    int t = __shfl_up(v, off, 64);
    if (tid >= off) v += t;
  }
  if (tid < nblk) blksum[tid] = v - orig;
  if (tid == 63) rowptr[N_NODES] = v;
}

__global__ __launch_bounds__(256) void scan_add(
    int* __restrict__ rowptr, const int* __restrict__ blksum)
{
  int i = blockIdx.x * 256 + threadIdx.x;
  if (i < N_NODES) rowptr[i] += blksum[i >> 11];
}

__global__ void bucket_init(const int* __restrict__ rowptr,
                            int* __restrict__ bbase, int* __restrict__ bcnt)
{
  int b = threadIdx.x;               // 256 >= NBUCK
  if (b < NBUCK) { bbase[b] = rowptr[b << BSH]; bcnt[b] = 0; }
}

__global__ __launch_bounds__(256) void csr_fill1(
    const int* __restrict__ ei, const float* __restrict__ ew,
    const int* __restrict__ bbase, int* __restrict__ bcnt,
    int2* __restrict__ esw, int* __restrict__ edst)
{
  int e = blockIdx.x * 256 + threadIdx.x;
  if (e >= N_EDGES) return;
  int d = ei[N_EDGES + e];
  int bu = d >> BSH;
  int pos = bbase[bu] + atomicAdd(&bcnt[bu], 1);
  esw[pos]  = make_int2(ei[e], __float_as_int(ew[e]));
  edst[pos] = d;
}

__global__ __launch_bounds__(256) void csr_fill2(
    const int2* __restrict__ esw, const int* __restrict__ edst,
    const int* __restrict__ rowptr, int* __restrict__ cnt,
    int2* __restrict__ epak)
{
  int p = blockIdx.x * 256 + threadIdx.x;
  if (p >= N_EDGES) return;
  int d = edst[p];
  int pos = rowptr[d] + atomicAdd(&cnt[d], 1);
  epak[pos] = esw[p];
}

// ---------------------------------------------------------------------------
// Pull aggregation on bf16 x: z[n] = sum w_e * x[src_e], fp32 accumulate,
// bf16 packed output. One wave/node, lane covers cols {2*lane, 2*lane+1}.
// ---------------------------------------------------------------------------
__global__ __launch_bounds__(256) void agg_pull(
    const unsigned* __restrict__ xbp, const int* __restrict__ rowptr,
    const int2* __restrict__ epak, unsigned* __restrict__ zbp)
{
  int node = blockIdx.x * 4 + (threadIdx.x >> 6);
  if (node >= N_NODES) return;
  int lane = threadIdx.x & 63;
  int s0 = rowptr[node], s1 = rowptr[node + 1];
  float v0 = 0.f, v1 = 0.f;
  int e = s0;
  for (; e + 3 < s1; e += 4) {
    int2 e0 = epak[e], e1 = epak[e + 1], e2 = epak[e + 2], e3 = epak[e + 3];
    unsigned p0 = xbp[(size_t)e0.x * 64 + lane];
    unsigned p1 = xbp[(size_t)e1.x * 64 + lane];
    unsigned p2 = xbp[(size_t)e2.x * 64 + lane];
    unsigned p3 = xbp[(size_t)e3.x * 64 + lane];
    float w0 = __int_as_float(e0.y), w1 = __int_as_float(e1.y);
    float w2 = __int_as_float(e2.y), w3 = __int_as_float(e3.y);
    v0 = fmaf(w0, bflo(p0), v0); v1 = fmaf(w0, bfhi(p0), v1);
    v0 = fmaf(w1, bflo(p1), v0); v1 = fmaf(w1, bfhi(p1), v1);
    v0 = fmaf(w2, bflo(p2), v0); v1 = fmaf(w2, bfhi(p2), v1);
    v0 = fmaf(w3, bflo(p3), v0); v1 = fmaf(w3, bfhi(p3), v1);
  }
  for (; e < s1; e++) {
    int2 ep = epak[e];
    unsigned p = xbp[(size_t)ep.x * 64 + lane];
    float w = __int_as_float(ep.y);
    v0 = fmaf(w, bflo(p), v0); v1 = fmaf(w, bfhi(p), v1);
  }
  zbp[(size_t)node * 64 + lane] =
      (unsigned)f2bf(v0) | ((unsigned)f2bf(v1) << 16);
}

// ---------------------------------------------------------------------------
// Fused GRU layer (bf16 MFMA), v3: block = 512 threads = 8 waves; wave w
// owns t-tile w (16 gate-cols x 3 gates) and holds its 24 B-fragments in
// registers for the whole kernel (96 VGPR). Block covers 128 rows as 8
// sequential 16-row tiles; per tile: 8 coalesced A-loads -> 24 MFMAs ->
// barrier -> GRU epilogue. The barrier makes the in-place xb update safe
// (all waves' A-reads of this tile land before any wave writes it).
// ---------------------------------------------------------------------------
__global__ __launch_bounds__(512) void gru_fused(
    const short* __restrict__ zb, short* __restrict__ xb,
    float* __restrict__ x,
    const short* __restrict__ Fb, const short* __restrict__ Wb,
    const float* __restrict__ bih, const float* __restrict__ bhh)
{
  const int ti   = threadIdx.x >> 6;     // 0..7 : this wave's t-tile
  const int lane = threadIdx.x & 63;
  const int m    = lane & 15;
  const int g4   = lane >> 4;

  // B fragments, resident for the whole kernel
  bf16x8 fR[4], fZ[4], fN[4], wR[4], wZ[4], wN[4];
  {
    const short* fb = Fb + ti * 2048 + lane * 8;
    const short* wb = Wb + ti * 2048 + lane * 8;
#pragma unroll
    for (int ks = 0; ks < 4; ks++) {
      fR[ks] = *(const bf16x8*)(fb + ks * 512);
      fZ[ks] = *(const bf16x8*)(fb + ks * 512 + 16384);
      fN[ks] = *(const bf16x8*)(fb + ks * 512 + 32768);
      wR[ks] = *(const bf16x8*)(wb + ks * 512);
      wZ[ks] = *(const bf16x8*)(wb + ks * 512 + 16384);
      wN[ks] = *(const bf16x8*)(wb + ks * 512 + 32768);
    }
  }
  const int col = ti * 16 + m;
  const float b_r = bih[col] + bhh[col];
  const float b_z = bih[128 + col] + bhh[128 + col];
  const float b_i = bih[256 + col];
  const float b_h = bhh[256 + col];

#pragma unroll 1
  for (int it = 0; it < 8; it++) {
    int r0 = blockIdx.x * 128 + it * 16;
    int arow = r0 + m;
    size_t ac = (size_t)(arow < N_NODES ? arow : N_NODES - 1) * 128 + g4 * 8;
    bf16x8 az[4], ax[4];
#pragma unroll
    for (int ks = 0; ks < 4; ks++) {
      az[ks] = *(const bf16x8*)(zb + ac + ks * 32);
      ax[ks] = *(const bf16x8*)(xb + ac + ks * 32);
    }
    f32x4 aR = (f32x4){0.f, 0.f, 0.f, 0.f};
    f32x4 aZ = (f32x4){0.f, 0.f, 0.f, 0.f};
    f32x4 aN = (f32x4){0.f, 0.f, 0.f, 0.f};
    f32x4 aH = (f32x4){0.f, 0.f, 0.f, 0.f};
#pragma unroll
    for (int ks = 0; ks < 4; ks++) {
      aR = __builtin_amdgcn_mfma_f32_16x16x32_bf16(az[ks], fR[ks], aR, 0, 0, 0);
      aZ = __builtin_amdgcn_mfma_f32_16x16x32_bf16(az[ks], fZ[ks], aZ, 0, 0, 0);
      aN = __builtin_amdgcn_mfma_f32_16x16x32_bf16(az[ks], fN[ks], aN, 0, 0, 0);
      aR = __builtin_amdgcn_mfma_f32_16x16x32_bf16(ax[ks], wR[ks], aR, 0, 0, 0);
      aZ = __builtin_amdgcn_mfma_f32_16x16x32_bf16(ax[ks], wZ[ks], aZ, 0, 0, 0);
      aH = __builtin_amdgcn_mfma_f32_16x16x32_bf16(ax[ks], wN[ks], aH, 0, 0, 0);
    }
    __syncthreads();   // all waves' xb reads of this tile done before writes
    // epilogue (C/D: col=lane&15, row=g4*4+reg)
#pragma unroll
    for (int r = 0; r < 4; r++) {
      int gr = r0 + g4 * 4 + r;
      if (gr < N_NODES) {
        float rg = 1.f / (1.f + __expf(-(aR[r] + b_r)));
        float zg = 1.f / (1.f + __expf(-(aZ[r] + b_z)));
        float ng = tanhf(aN[r] + b_i + rg * (aH[r] + b_h));
        size_t o = (size_t)gr * 128 + col;
        float xo = x[o];
        float xn = (1.f - zg) * ng + zg * xo;
        x[o] = xn;
        xb[o] = (short)f2bf(xn);
      }
    }
  }
}

// ---------------------------------------------------------------------------
// BatchNorm (fp32 master x)
// ---------------------------------------------------------------------------
__global__ __launch_bounds__(256) void bn_stats(
    const float* __restrict__ x, float* __restrict__ sums)
{
  __shared__ float ls[256], lq[256];
  int tid  = threadIdx.x;
  int col  = tid & 127, half = tid >> 7;
  int r0   = blockIdx.x * 128;
  int rend = min(N_NODES, r0 + 128);
  float s = 0.f, q = 0.f;
  for (int r = r0 + half; r < rend; r += 2) {
    float v = x[(size_t)r * HDIM + col];
    s += v; q += v * v;
  }
  ls[tid] = s; lq[tid] = q;
  __syncthreads();
  if (tid < 128) {
    atomicAdd(&sums[col],       ls[tid] + ls[tid + 128]);
    atomicAdd(&sums[128 + col], lq[tid] + lq[tid + 128]);
  }
}

__global__ void bn_finalize(float* __restrict__ sums,
                            const float* __restrict__ gamma,
                            const float* __restrict__ beta)
{
  int j = threadIdx.x;
  float mean = sums[j] / (float)N_NODES;
  float var  = sums[128 + j] / (float)N_NODES - mean * mean;
  float inv  = rsqrtf(var + 1e-5f);
  sums[256 + j] = gamma[j] * inv;
  sums[384 + j] = beta[j] - mean * gamma[j] * inv;
}

__global__ __launch_bounds__(256) void bn_apply(
    float* __restrict__ x, const float* __restrict__ sums)
{
  int i = blockIdx.x * 256 + threadIdx.x;
  int j = i & 127;
  x[i] = x[i] * sums[256 + j] + sums[384 + j];
}

// ---------------------------------------------------------------------------
// Residual fold constants: E2 = embW @ mlpW  [128][40], c2 = mlpB + embB@mlpW
// ---------------------------------------------------------------------------
__global__ void prep_e2(const float* __restrict__ embW,
                        const float* __restrict__ embB,
                        const float* __restrict__ mlpW,
                        const float* __restrict__ mlpB,
                        float* __restrict__ e2, float* __restrict__ c2)
{
  int tid = threadIdx.x;
#pragma unroll
  for (int t = 0; t < 20; t++) {
    int idx = tid * 20 + t;
    int f = idx / 40, j = idx - f * 40;
    float s = 0.f;
    for (int k = 0; k < 128; k++)
      s = fmaf(embW[f * 128 + k], mlpW[k * 40 + j], s);
    e2[idx] = s;
  }
  if (tid < 40) {
    float s = mlpB[tid];
    for (int k = 0; k < 128; k++)
      s = fmaf(embB[k], mlpW[k * 40 + tid], s);
    c2[tid] = s;
  }
}

// ---------------------------------------------------------------------------
extern "C" void kernel_launch(void* const* d_in, const int* in_sizes, int n_in,
                              void* d_out, int out_size, void* d_ws, size_t ws_size,
                              hipStream_t stream)
{
  const float* h     = (const float*)d_in[0];
  const int*   ei    = (const int*)d_in[1];
  const float* ew    = (const float*)d_in[2];
  const float* embW  = (const float*)d_in[3];
  const float* embB  = (const float*)d_in[4];
  const float* convW = (const float*)d_in[5];   // [3][128][128]
  const float* Wih   = (const float*)d_in[6];   // [384][128]
  const float* Whh   = (const float*)d_in[7];   // [384][128]
  const float* bih   = (const float*)d_in[8];
  const float* bhh   = (const float*)d_in[9];
  const float* gamma = (const float*)d_in[10];
  const float* beta  = (const float*)d_in[11];
  const float* mlpW  = (const float*)d_in[12];
  const float* mlpB  = (const float*)d_in[13];
  float* out = (float*)d_out;

  float* ws = (float*)d_ws;
  const size_t NH = (size_t)N_NODES * HDIM;      // 12.8M
  float*    x      = ws;                          // [N][128] fp32 master
  unsigned* xbp    = (unsigned*)(ws + NH);        // [N][64] packed bf16
  unsigned* zbp    = xbp + NH / 2;                // [N][64] packed bf16
  int2*     epak   = (int2*)(zbp + NH / 2);       // [E] {src, w}
  int*      rowptr = (int*)(epak + N_EDGES);      // N+4
  int*      cnt    = rowptr + N_NODES + 4;        // N
  int*      deg    = cnt + N_NODES;               // N
  int*      blksum = deg + N_NODES;               // 64
  int*      bbase  = blksum + 64;                 // NBUCK
  int*      bcnt   = bbase + NBUCK;               // NBUCK
  float*    Ffold  = (float*)(bcnt + NBUCK);      // [3][384][128] fp32
  short*    Fbp    = (short*)(Ffold + 3 * 384 * 128);  // frag-order bf16
  short*    Wbp    = Fbp + 3 * 384 * 128;         // frag-order bf16 of Whh
  float*    sums   = (float*)(Wbp + 384 * 128);
  float*    e2     = sums + 512;
  float*    c2     = e2 + 5120;
  // CSR-build scratch aliases x/xbp (CSR runs before emb writes them):
  int2*     esw    = (int2*)x;                    // E int2 = 25.6MB < 51.2MB
  int*      edst   = (int*)xbp;                   // E int  = 12.8MB < 25.6MB
  // total ~131 MB

  dim3 blk(256);
  const int MB  = (N_NODES + 63) / 64;
  const int MBG = (N_NODES + 127) / 128;          // gru blocks (782)
  const int EB  = (N_EDGES + 255) / 256;
  const int RB  = (384 * 128 + 255) / 256;
  const int SB  = (N_NODES + 2047) / 2048;        // 49 scan blocks (<=64)

  // ---- constants ----
  prep_e2<<<1, 256, 0, stream>>>(embW, embB, mlpW, mlpB, e2, c2);
  for (int l = 0; l < 3; l++)
    gemm_k128<true, false><<<dim3(6, 1), blk, 0, stream>>>(
        Wih, convW + (size_t)l * HDIM * HDIM, nullptr,
        Ffold + (size_t)l * 384 * HDIM, 384, 128);
  for (int l = 0; l < 3; l++)
    repack_frag_b<<<RB, blk, 0, stream>>>(
        Ffold + (size_t)l * 384 * HDIM, Fbp + (size_t)l * 384 * HDIM);
  repack_frag_b<<<RB, blk, 0, stream>>>(Whh, Wbp);

  // ---- CSR build (before emb: esw/edst alias the x/xbp region) ----
  zero_i32<<<(2 * N_NODES + 255) / 256, blk, 0, stream>>>(cnt, 2 * N_NODES);
  csr_hist<<<EB, blk, 0, stream>>>(ei, deg);
  scan_blk<<<SB, blk, 0, stream>>>(deg, rowptr, blksum);
  scan_top<<<1, 64, 0, stream>>>(blksum, SB, rowptr);
  scan_add<<<(N_NODES + 255) / 256, blk, 0, stream>>>(rowptr, blksum);
  bucket_init<<<1, 256, 0, stream>>>(rowptr, bbase, bcnt);
  csr_fill1<<<EB, blk, 0, stream>>>(ei, ew, bbase, bcnt, esw, edst);
  csr_fill2<<<EB, blk, 0, stream>>>(esw, edst, rowptr, cnt, epak);

  // ---- embedding: x = h @ embW + embB ; bf16 mirror ----
  gemm_k128<false, false><<<dim3(MB, 1), blk, 0, stream>>>(h, embW, embB, x, N_NODES, 128);
  f32_to_bf16_pack<<<(int)(NH / 2 + 255) / 256, blk, 0, stream>>>(x, xbp, (int)(NH / 2));

  // ---- 3 GRU layers: pull-agg (bf16) + fused MFMA GRU ----
  for (int l = 0; l < 3; l++) {
    agg_pull<<<(N_NODES + 3) / 4, blk, 0, stream>>>(xbp, rowptr, epak, zbp);
    gru_fused<<<MBG, dim3(512), 0, stream>>>(
        (const short*)zbp, (short*)xbp, x,
        Fbp + (size_t)l * 384 * HDIM, Wbp, bih, bhh);
  }

  // ---- BatchNorm + residual-folded head ----
  zero_f32<<<2, blk, 0, stream>>>(sums, 512);
  bn_stats<<<(N_NODES + 127) / 128, blk, 0, stream>>>(x, sums);
  bn_finalize<<<1, 128, 0, stream>>>(sums, gamma, beta);
  bn_apply<<<(int)(NH / 256), blk, 0, stream>>>(x, sums);

  gemm_k128<false, false><<<dim3(MB, 1), blk, 0, stream>>>(x, mlpW, c2, out, N_NODES, 40);
  gemm_k128<false, true><<<dim3(MB, 1), blk, 0, stream>>>(h, e2, nullptr, out, N_NODES, 40);
}